// Round 12
// baseline (314.509 us; speedup 1.0000x reference)
//
#include <hip/hip_runtime.h>
#include <hip/hip_bf16.h>

#define N_NODES 50000
#define N_EDGES 800000
#define DIM_IN  384
#define DIM_H   256

typedef __bf16 bf16x8 __attribute__((ext_vector_type(8)));
typedef float  f32x4  __attribute__((ext_vector_type(4)));

static __device__ __forceinline__ ushort f2bf(float f) {
  uint u = __float_as_uint(f);
  u += 0x7fffu + ((u >> 16) & 1u);
  return (ushort)(u >> 16);
}
static __device__ __forceinline__ float bf_lo(uint u) { return __uint_as_float(u << 16); }
static __device__ __forceinline__ float bf_hi(uint u) { return __uint_as_float(u & 0xffff0000u); }

typedef const __attribute__((address_space(1))) void* gas_p;
typedef __attribute__((address_space(3))) void* las_p;
static __device__ __forceinline__ void gload16(const void* g, void* l) {
  __builtin_amdgcn_global_load_lds((gas_p)g, (las_p)l, 16, 0, 0);
}

static __device__ __forceinline__ float log1p_fast(float x) {
  return __logf(1.0f + x);
}

// ---------------- weight prepack helpers ----------------
static __device__ __forceinline__ int permc(int p) {
  return ((p >> 7) << 7) + ((p & 7) << 4) + ((p >> 3) & 15);
}
static __device__ __forceinline__ void pack_one(const float* W, ushort* out, int local, bool perm) {
  int k = local >> 8, col = local & 255;
  int kc = k >> 5, kgd = (k >> 3) & 3, e = k & 7;
  int kgs = kgd ^ ((col >> 1) & 3);
  int krow = perm ? permc(k) : k;
  out[((size_t)kc * 256 + col) * 32 + kgs * 8 + e] = f2bf(W[krow * 256 + col]);
}

// ---------------- prep: [hist blocks][pack blocks] (log1p folded into gemm0) ----------------
#define HIST_BLOCKS 3125
#define PACK_TOT (2 * DIM_IN * 256 + 4 * DIM_H * 256)
#define PACK_BLOCKS ((PACK_TOT + 255) / 256)

__global__ void prep_kernel(const int* __restrict__ dst, int* __restrict__ deg,
                            const float* W0s, const float* W0n, const float* W1s,
                            const float* W1n, const float* W2s, const float* W2n,
                            ushort* o0s, ushort* o0n, ushort* o1s, ushort* o1n,
                            ushort* o2s, ushort* o2n) {
  int bid = blockIdx.x;
  if (bid < HIST_BLOCKS) {
    int i = bid * 256 + threadIdx.x;
    if (i < N_EDGES) atomicAdd(&deg[dst[i]], 1);
  } else {
    int idx = (bid - HIST_BLOCKS) * 256 + threadIdx.x;
    const int SZ0 = DIM_IN * 256;
    const int SZ1 = DIM_H * 256;
    if (idx < SZ0) pack_one(W0s, o0s, idx, false);
    else if (idx < 2 * SZ0) pack_one(W0n, o0n, idx - SZ0, false);
    else if (idx < PACK_TOT) {
      int j = idx - 2 * SZ0;
      int w = j / SZ1, local = j - w * SZ1;
      if (w == 0) pack_one(W1s, o1s, local, true);
      else if (w == 1) pack_one(W1n, o1n, local, true);
      else if (w == 2) pack_one(W2s, o2s, local, true);
      else pack_one(W2n, o2n, local, true);
    }
  }
}

// ---------------- hierarchical scan ----------------
__global__ void scan1_kernel(const int* __restrict__ deg, int* __restrict__ tmp,
                             int* __restrict__ bsum) {
  __shared__ int buf[256];
  int t = threadIdx.x, i = blockIdx.x * 256 + t;
  int v = (i < N_NODES) ? deg[i] : 0;
  buf[t] = v;
  __syncthreads();
  int x = v;
#pragma unroll
  for (int off = 1; off < 256; off <<= 1) {
    int y = (t >= off) ? buf[t - off] : 0;
    __syncthreads();
    x += y;
    buf[t] = x;
    __syncthreads();
  }
  if (i < N_NODES) tmp[i] = x - v;
  if (t == 255) bsum[blockIdx.x] = x;
}

__global__ void scan2_kernel(int* __restrict__ bsum, int nb) {
  __shared__ int buf[256];
  int t = threadIdx.x;
  int v = (t < nb) ? bsum[t] : 0;
  buf[t] = v;
  __syncthreads();
  int x = v;
#pragma unroll
  for (int off = 1; off < 256; off <<= 1) {
    int y = (t >= off) ? buf[t - off] : 0;
    __syncthreads();
    x += y;
    buf[t] = x;
    __syncthreads();
  }
  if (t < nb) bsum[t] = x - v;
}

__global__ void scan3_kernel(const int* __restrict__ tmp, const int* __restrict__ bsum,
                             int* __restrict__ rowptr, int* __restrict__ cursor) {
  int i = blockIdx.x * 256 + threadIdx.x;
  if (i >= N_NODES) return;
  int r = tmp[i] + bsum[i >> 8];
  rowptr[i] = r;
  cursor[i] = r;
}

// ---------------- dual GEMM body: S = bf16(A@Ws + b), Yq = int8(A@Wn) ----------------
// F32A: A-operand comes from Xf (f32), converted via log1p_fast->bf16 during
// reg-staging with swizzled ds_write (layer 0). Else A is bf16 via global_load_lds.
template <int K, bool F32A>
static __device__ void gemm_dual_body(int blk, ushort* Al, ushort* Bl, float* red,
                                      const ushort* __restrict__ A,
                                      const float* __restrict__ Xf,
                                      const ushort* __restrict__ Bs,
                                      const ushort* __restrict__ Bn,
                                      const float* __restrict__ bias,
                                      ushort* __restrict__ Sout,
                                      unsigned char* __restrict__ Yq,
                                      float* __restrict__ scales) {
  constexpr int KC = K / 32;
  constexpr int NT = 2 * KC;
  const int tid = threadIdx.x;
  const int wv = tid >> 6, lane = tid & 63, lj = lane & 15, lg = lane >> 4;
  const int wm = wv >> 1, wn = wv & 1;
  const int r0 = blk * 128;

  // A staging descriptors
  int grow[2], akgd[2];       // bf16 gload path
  const float* sx[2];         // f32 reg path
  int ldsoff[2];
#pragma unroll
  for (int j = 0; j < 2; ++j) {
    int d = tid + j * 256;
    int row = d >> 2, kg = d & 3;
    int r = r0 + row;
    r = r < N_NODES ? r : N_NODES - 1;
    akgd[j] = kg ^ ((row >> 1) & 3);
    grow[j] = r;
    sx[j] = Xf + (size_t)r * K + kg * 8;
    ldsoff[j] = row * 32 + (kg ^ ((row >> 1) & 3)) * 8;
  }

  int aoff[4], boff[8];
#pragma unroll
  for (int mf = 0; mf < 4; ++mf) {
    int row = wm * 64 + mf * 16 + lj;
    aoff[mf] = row * 32 + (lg ^ ((row >> 1) & 3)) * 8;
  }
#pragma unroll
  for (int f = 0; f < 8; ++f) {
    int col = wn * 128 + f * 16 + lj;
    boff[f] = col * 32 + (lg ^ ((col >> 1) & 3)) * 8;
  }

  auto stage = [&](int t, int bb) {
    int p = t >= KC;
    int kc = t - p * KC;
    const ushort* Bp = p ? Bn : Bs;
#pragma unroll
    for (int j = 0; j < 4; ++j)
      gload16(Bp + (size_t)kc * 8192 + (tid + j * 256) * 8,
              (char*)(Bl + bb * 8192) + j * 4096 + wv * 1024);
    if constexpr (F32A) {
#pragma unroll
      for (int j = 0; j < 2; ++j) {
        const float* s = sx[j] + kc * 32;
        float4 a = *reinterpret_cast<const float4*>(s);
        float4 b = *reinterpret_cast<const float4*>(s + 4);
        uint4 o;
        o.x = (uint)f2bf(log1p_fast(a.x)) | ((uint)f2bf(log1p_fast(a.y)) << 16);
        o.y = (uint)f2bf(log1p_fast(a.z)) | ((uint)f2bf(log1p_fast(a.w)) << 16);
        o.z = (uint)f2bf(log1p_fast(b.x)) | ((uint)f2bf(log1p_fast(b.y)) << 16);
        o.w = (uint)f2bf(log1p_fast(b.z)) | ((uint)f2bf(log1p_fast(b.w)) << 16);
        *reinterpret_cast<uint4*>(Al + bb * 4096 + ldsoff[j]) = o;
      }
    } else {
#pragma unroll
      for (int j = 0; j < 2; ++j)
        gload16(A + (size_t)grow[j] * K + kc * 32 + akgd[j] * 8,
                (char*)(Al + bb * 4096) + j * 4096 + wv * 1024);
    }
  };

  float bvv[8];
#pragma unroll
  for (int f = 0; f < 8; ++f) bvv[f] = bias[wn * 128 + f * 16 + lj];

  f32x4 acc[4][8];
#pragma unroll
  for (int mf = 0; mf < 4; ++mf)
#pragma unroll
    for (int f = 0; f < 8; ++f) acc[mf][f] = (f32x4){0.f, 0.f, 0.f, 0.f};

  stage(0, 0);
  __syncthreads();
  int b = 0;
  for (int t = 0; t < NT; ++t) {
    bf16x8 av[4], bv[8];
#pragma unroll
    for (int mf = 0; mf < 4; ++mf)
      av[mf] = *reinterpret_cast<const bf16x8*>(Al + b * 4096 + aoff[mf]);
#pragma unroll
    for (int f = 0; f < 8; ++f)
      bv[f] = *reinterpret_cast<const bf16x8*>(Bl + b * 8192 + boff[f]);
    if (t + 1 < NT) stage(t + 1, b ^ 1);
#pragma unroll
    for (int mf = 0; mf < 4; ++mf)
#pragma unroll
      for (int f = 0; f < 8; ++f)
        acc[mf][f] = __builtin_amdgcn_mfma_f32_16x16x32_bf16(av[mf], bv[f], acc[mf][f], 0, 0, 0);
    if (t == KC - 1) {
#pragma unroll
      for (int mf = 0; mf < 4; ++mf)
#pragma unroll
        for (int e = 0; e < 4; ++e) {
          int row = r0 + wm * 64 + mf * 16 + lg * 4 + e;
          if (row < N_NODES) {
            ushort* pS = Sout + (size_t)row * 256 + wn * 128 + lj * 8;
            uint4 o;
            o.x = (uint)f2bf(acc[mf][0][e] + bvv[0]) | ((uint)f2bf(acc[mf][1][e] + bvv[1]) << 16);
            o.y = (uint)f2bf(acc[mf][2][e] + bvv[2]) | ((uint)f2bf(acc[mf][3][e] + bvv[3]) << 16);
            o.z = (uint)f2bf(acc[mf][4][e] + bvv[4]) | ((uint)f2bf(acc[mf][5][e] + bvv[5]) << 16);
            o.w = (uint)f2bf(acc[mf][6][e] + bvv[6]) | ((uint)f2bf(acc[mf][7][e] + bvv[7]) << 16);
            *reinterpret_cast<uint4*>(pS) = o;
          }
        }
#pragma unroll
      for (int mf = 0; mf < 4; ++mf)
#pragma unroll
        for (int f = 0; f < 8; ++f) acc[mf][f] = (f32x4){0.f, 0.f, 0.f, 0.f};
    }
    __syncthreads();
    b ^= 1;
  }

  float rmax[4][4];
#pragma unroll
  for (int mf = 0; mf < 4; ++mf)
#pragma unroll
    for (int e = 0; e < 4; ++e) {
      float m = 0.f;
#pragma unroll
      for (int f = 0; f < 8; ++f) m = fmaxf(m, fabsf(acc[mf][f][e]));
      m = fmaxf(m, __shfl_xor(m, 1));
      m = fmaxf(m, __shfl_xor(m, 2));
      m = fmaxf(m, __shfl_xor(m, 4));
      m = fmaxf(m, __shfl_xor(m, 8));
      rmax[mf][e] = m;
    }
  if (lj == 0) {
#pragma unroll
    for (int mf = 0; mf < 4; ++mf)
#pragma unroll
      for (int e = 0; e < 4; ++e)
        red[(wn * 2 + wm) * 64 + mf * 16 + lg * 4 + e] = rmax[mf][e];
  }
  __syncthreads();
#pragma unroll
  for (int mf = 0; mf < 4; ++mf)
#pragma unroll
    for (int e = 0; e < 4; ++e) {
      float m = fmaxf(fmaxf(red[(0 * 2 + wm) * 64 + mf * 16 + lg * 4 + e],
                            red[(1 * 2 + wm) * 64 + mf * 16 + lg * 4 + e]), 1e-30f);
      float inv_s = 127.0f / m;
      int row = r0 + wm * 64 + mf * 16 + lg * 4 + e;
      if (row < N_NODES) {
        uint lo = 0, hi = 0;
#pragma unroll
        for (int f = 0; f < 4; ++f) {
          int q = (int)rintf(acc[mf][f][e] * inv_s) + 128;
          q = max(0, min(255, q));
          lo |= (uint)q << (8 * f);
        }
#pragma unroll
        for (int f = 4; f < 8; ++f) {
          int q = (int)rintf(acc[mf][f][e] * inv_s) + 128;
          q = max(0, min(255, q));
          hi |= (uint)q << (8 * (f - 4));
        }
        *reinterpret_cast<uint2*>(Yq + (size_t)row * 256 + wn * 128 + lj * 8) = make_uint2(lo, hi);
        if (wn == 0 && lj == 0) scales[row] = m * (1.0f / 127.0f);
      }
    }
}

// ---------------- striped {gemm0(A=log1p(x)) : CSR fill}, 1:2 ratio ----------------
#define GEMM_BLOCKS ((N_NODES + 127) / 128)     // 391
#define GF_TOT (GEMM_BLOCKS * 3)                // {1 gemm, 2 fill}; 782 fill x 1024 edges

__global__ __launch_bounds__(256, 2) void gemm0_fill_kernel(
    const float* __restrict__ x, const ushort* __restrict__ Bs,
    const ushort* __restrict__ Bn, const float* __restrict__ bias,
    ushort* __restrict__ Sout, unsigned char* __restrict__ Yq, float* __restrict__ scales,
    const int* __restrict__ src, const int* __restrict__ dst,
    int* __restrict__ cursor, ushort* __restrict__ csr) {
  __shared__ ushort Al[2 * 4096];
  __shared__ ushort Bl[2 * 8192];
  __shared__ float red[256];
  int g = blockIdx.x / 3, r = blockIdx.x - g * 3;
  if (r == 0) {
    gemm_dual_body<DIM_IN, true>(g, Al, Bl, red, nullptr, x, Bs, Bn, bias, Sout, Yq, scales);
  } else {
    int fb = g * 2 + (r - 1);
    int base = fb * 1024 + threadIdx.x * 4;
    if (base + 3 < N_EDGES) {
      int4 d4 = *reinterpret_cast<const int4*>(dst + base);
      int4 s4 = *reinterpret_cast<const int4*>(src + base);
      int p0 = atomicAdd(&cursor[d4.x], 1);
      int p1 = atomicAdd(&cursor[d4.y], 1);
      int p2 = atomicAdd(&cursor[d4.z], 1);
      int p3 = atomicAdd(&cursor[d4.w], 1);
      csr[p0] = (ushort)s4.x;
      csr[p1] = (ushort)s4.y;
      csr[p2] = (ushort)s4.z;
      csr[p3] = (ushort)s4.w;
    } else {
#pragma unroll
      for (int j = 0; j < 4; ++j) {
        int i = base + j;
        if (i < N_EDGES) {
          int d = dst[i];
          int p = atomicAdd(&cursor[d], 1);
          csr[p] = (ushort)src[i];
        }
      }
    }
  }
}

__global__ __launch_bounds__(256, 2) void gemm_dual_kernel(
    const ushort* __restrict__ A, const ushort* __restrict__ Bs,
    const ushort* __restrict__ Bn, const float* __restrict__ bias,
    ushort* __restrict__ Sout, unsigned char* __restrict__ Yq, float* __restrict__ scales) {
  __shared__ ushort Al[2 * 4096];
  __shared__ ushort Bl[2 * 8192];
  __shared__ float red[256];
  gemm_dual_body<DIM_H, false>(blockIdx.x, Al, Bl, red, A, nullptr, Bs, Bn, bias, Sout, Yq, scales);
}

// ---------------- gather: out = epilogue(S + mean(dequant(Yq[src]))) ----------------
template <bool FINAL>
__global__ __launch_bounds__(256) void gather_kernel(const unsigned char* __restrict__ Yq,
                                                     const float* __restrict__ scales,
                                                     const ushort* __restrict__ Sin,
                                                     const int* __restrict__ rowptr,
                                                     const int* __restrict__ deg,
                                                     const ushort* __restrict__ csr,
                                                     void* __restrict__ outv) {
  int node = blockIdx.x * 8 + (threadIdx.x >> 5);
  if (node >= N_NODES) return;
  int hl = threadIdx.x & 31;
  int start = rowptr[node];
  int d = deg[node];
  float acc[8];
#pragma unroll
  for (int i = 0; i < 8; ++i) acc[i] = 0.0f;
  float stot = 0.f;

  auto ub = [](uint u, int j) { return (float)((u >> (8 * j)) & 0xffu); };
  int e = 0;
  for (; e + 4 <= d; e += 4) {
    int s0 = csr[start + e], s1 = csr[start + e + 1];
    int s2 = csr[start + e + 2], s3 = csr[start + e + 3];
    float c0 = scales[s0], c1 = scales[s1], c2 = scales[s2], c3 = scales[s3];
    uint2 q0 = *reinterpret_cast<const uint2*>(Yq + (size_t)s0 * 256 + hl * 8);
    uint2 q1 = *reinterpret_cast<const uint2*>(Yq + (size_t)s1 * 256 + hl * 8);
    uint2 q2 = *reinterpret_cast<const uint2*>(Yq + (size_t)s2 * 256 + hl * 8);
    uint2 q3 = *reinterpret_cast<const uint2*>(Yq + (size_t)s3 * 256 + hl * 8);
    stot += c0 + c1 + c2 + c3;
#pragma unroll
    for (int j = 0; j < 4; ++j) {
      acc[j]     += c0 * ub(q0.x, j) + c1 * ub(q1.x, j) + c2 * ub(q2.x, j) + c3 * ub(q3.x, j);
      acc[4 + j] += c0 * ub(q0.y, j) + c1 * ub(q1.y, j) + c2 * ub(q2.y, j) + c3 * ub(q3.y, j);
    }
  }
  for (; e < d; ++e) {
    int s = csr[start + e];
    float c = scales[s];
    uint2 q = *reinterpret_cast<const uint2*>(Yq + (size_t)s * 256 + hl * 8);
    stot += c;
#pragma unroll
    for (int j = 0; j < 4; ++j) {
      acc[j]     += c * ub(q.x, j);
      acc[4 + j] += c * ub(q.y, j);
    }
  }

  float invd = 1.0f / fmaxf((float)d, 1.0f);
  float nb[8];
#pragma unroll
  for (int j = 0; j < 8; ++j) nb[j] = (acc[j] - 128.0f * stot) * invd;

  uint4 sv = *reinterpret_cast<const uint4*>(Sin + (size_t)node * 256 + hl * 8);
  uint su[4] = {sv.x, sv.y, sv.z, sv.w};

  if constexpr (FINAL) {
    float* out = (float*)outv + (size_t)node * 256 + (hl >> 4) * 128 + (hl & 15);
#pragma unroll
    for (int i = 0; i < 4; ++i) {
      out[(2 * i) * 16]     = nb[2 * i] + bf_lo(su[i]);
      out[(2 * i + 1) * 16] = nb[2 * i + 1] + bf_hi(su[i]);
    }
  } else {
    float v[8];
    float ssq = 0.f;
#pragma unroll
    for (int i = 0; i < 4; ++i) {
      float a = fmaxf(nb[2 * i] + bf_lo(su[i]), 0.0f);
      float b = fmaxf(nb[2 * i + 1] + bf_hi(su[i]), 0.0f);
      v[2 * i] = a; v[2 * i + 1] = b;
      ssq += a * a + b * b;
    }
    ssq += __shfl_xor(ssq, 1);
    ssq += __shfl_xor(ssq, 2);
    ssq += __shfl_xor(ssq, 4);
    ssq += __shfl_xor(ssq, 8);
    ssq += __shfl_xor(ssq, 16);
    float rn = 1.0f / fmaxf(sqrtf(ssq), 1e-12f);
    uint o[4];
#pragma unroll
    for (int i = 0; i < 4; ++i) {
      uint lo = f2bf(v[2 * i] * rn);
      uint hi = f2bf(v[2 * i + 1] * rn);
      o[i] = lo | (hi << 16);
    }
    *reinterpret_cast<uint4*>((ushort*)outv + (size_t)node * 256 + hl * 8) =
        make_uint4(o[0], o[1], o[2], o[3]);
  }
}

// ---------------- launch ----------------
extern "C" void kernel_launch(void* const* d_in, const int* in_sizes, int n_in,
                              void* d_out, int out_size, void* d_ws, size_t ws_size,
                              hipStream_t stream) {
  const float* x   = (const float*)d_in[0];
  const int*   src = (const int*)d_in[1];
  const int*   dst = (const int*)d_in[2];
  const float* Ws0 = (const float*)d_in[3];
  const float* Wn0 = (const float*)d_in[4];
  const float* b0  = (const float*)d_in[5];
  const float* Ws1 = (const float*)d_in[6];
  const float* Wn1 = (const float*)d_in[7];
  const float* b1  = (const float*)d_in[8];
  const float* Ws2 = (const float*)d_in[9];
  const float* Wn2 = (const float*)d_in[10];
  const float* b2  = (const float*)d_in[11];

  uintptr_t p = ((uintptr_t)d_ws + 255) & ~(uintptr_t)255;
  auto carve = [&](size_t bytes) {
    void* r = (void*)p;
    p += (bytes + 255) & ~(size_t)255;
    return r;
  };
  ushort* S_mid = (ushort*)carve((size_t)N_NODES * DIM_H * 2);
  ushort* h1 = (ushort*)carve((size_t)N_NODES * DIM_H * 2);
  ushort* h2 = (ushort*)carve((size_t)N_NODES * DIM_H * 2);
  unsigned char* Yq = (unsigned char*)carve((size_t)N_NODES * 256);
  float* scales = (float*)carve((size_t)N_NODES * 4);
  ushort* Ws0p = (ushort*)carve((size_t)DIM_IN * 256 * 2);
  ushort* Wn0p = (ushort*)carve((size_t)DIM_IN * 256 * 2);
  ushort* Ws1p = (ushort*)carve((size_t)DIM_H * 256 * 2);
  ushort* Wn1p = (ushort*)carve((size_t)DIM_H * 256 * 2);
  ushort* Ws2p = (ushort*)carve((size_t)DIM_H * 256 * 2);
  ushort* Wn2p = (ushort*)carve((size_t)DIM_H * 256 * 2);
  int* deg    = (int*)carve((size_t)N_NODES * 4);
  int* rowptr = (int*)carve((size_t)N_NODES * 4);
  int* cursor = (int*)carve((size_t)N_NODES * 4);
  int* stmp   = (int*)carve((size_t)N_NODES * 4);
  int* bsum   = (int*)carve(256 * 4);
  ushort* csr = (ushort*)carve((size_t)N_EDGES * 2);

  hipMemsetAsync(deg, 0, (size_t)N_NODES * 4, stream);

  prep_kernel<<<HIST_BLOCKS + PACK_BLOCKS, 256, 0, stream>>>(
      dst, deg, Ws0, Wn0, Ws1, Wn1, Ws2, Wn2,
      Ws0p, Wn0p, Ws1p, Wn1p, Ws2p, Wn2p);

  const int scanBlocks = (N_NODES + 255) / 256;
  scan1_kernel<<<scanBlocks, 256, 0, stream>>>(deg, stmp, bsum);
  scan2_kernel<<<1, 256, 0, stream>>>(bsum, scanBlocks);
  scan3_kernel<<<scanBlocks, 256, 0, stream>>>(stmp, bsum, rowptr, cursor);

  gemm0_fill_kernel<<<GF_TOT, 256, 0, stream>>>(
      x, Ws0p, Wn0p, b0, S_mid, Yq, scales, src, dst, cursor, csr);

  const int gatherBlocks = (N_NODES + 7) / 8;

  gather_kernel<false><<<gatherBlocks, 256, 0, stream>>>(Yq, scales, S_mid, rowptr, deg, csr, h1);
  gemm_dual_kernel<<<GEMM_BLOCKS, 256, 0, stream>>>(h1, Ws1p, Wn1p, b1, S_mid, Yq, scales);
  gather_kernel<false><<<gatherBlocks, 256, 0, stream>>>(Yq, scales, S_mid, rowptr, deg, csr, h2);
  gemm_dual_kernel<<<GEMM_BLOCKS, 256, 0, stream>>>(h2, Ws2p, Wn2p, b2, S_mid, Yq, scales);
  gather_kernel<true><<<gatherBlocks, 256, 0, stream>>>(Yq, scales, S_mid, rowptr, deg, csr, d_out);
}

// Round 13
// 299.225 us; speedup vs baseline: 1.0511x; 1.0511x over previous
//
#include <hip/hip_runtime.h>
#include <hip/hip_bf16.h>

#define N_NODES 50000
#define N_EDGES 800000
#define DIM_IN  384
#define DIM_H   256

typedef __bf16 bf16x8 __attribute__((ext_vector_type(8)));
typedef float  f32x4  __attribute__((ext_vector_type(4)));

static __device__ __forceinline__ ushort f2bf(float f) {
  uint u = __float_as_uint(f);
  u += 0x7fffu + ((u >> 16) & 1u);
  return (ushort)(u >> 16);
}
static __device__ __forceinline__ float bf_lo(uint u) { return __uint_as_float(u << 16); }
static __device__ __forceinline__ float bf_hi(uint u) { return __uint_as_float(u & 0xffff0000u); }

typedef const __attribute__((address_space(1))) void* gas_p;
typedef __attribute__((address_space(3))) void* las_p;
static __device__ __forceinline__ void gload16(const void* g, void* l) {
  __builtin_amdgcn_global_load_lds((gas_p)g, (las_p)l, 16, 0, 0);
}

static __device__ __forceinline__ float log1p_fast(float x) {
  return __logf(1.0f + x);
}

// ---------------- weight prepack helpers ----------------
static __device__ __forceinline__ int permc(int p) {
  return ((p >> 7) << 7) + ((p & 7) << 4) + ((p >> 3) & 15);
}
static __device__ __forceinline__ void pack_one(const float* W, ushort* out, int local, bool perm) {
  int k = local >> 8, col = local & 255;
  int kc = k >> 5, kgd = (k >> 3) & 3, e = k & 7;
  int kgs = kgd ^ ((col >> 1) & 3);
  int krow = perm ? permc(k) : k;
  out[((size_t)kc * 256 + col) * 32 + kgs * 8 + e] = f2bf(W[krow * 256 + col]);
}

// ---------------- prep: striped {hist : log1p} + pack tail (R7-proven) ----------------
#define HIST_BLOCKS 3125
#define STRIPE1_TOT (HIST_BLOCKS * 7)
#define PACK_TOT (2 * DIM_IN * 256 + 4 * DIM_H * 256)
#define PACK_BLOCKS ((PACK_TOT + 255) / 256)

__global__ void prep_kernel(const float* __restrict__ x, ushort* __restrict__ h,
                            const int* __restrict__ dst, int* __restrict__ deg,
                            const float* W0s, const float* W0n, const float* W1s,
                            const float* W1n, const float* W2s, const float* W2n,
                            ushort* o0s, ushort* o0n, ushort* o1s, ushort* o1n,
                            ushort* o2s, ushort* o2n) {
  int bid = blockIdx.x;
  if (bid < STRIPE1_TOT) {
    int g = bid / 7, r = bid - g * 7;
    if (r == 0) {
      int i = g * 256 + threadIdx.x;
      if (i < N_EDGES) atomicAdd(&deg[dst[i]], 1);
    } else {
      int i = (g * 6 + (r - 1)) * 256 + threadIdx.x;
      float4 v = reinterpret_cast<const float4*>(x)[i];
      ushort4 o;
      o.x = f2bf(log1p_fast(v.x));
      o.y = f2bf(log1p_fast(v.y));
      o.z = f2bf(log1p_fast(v.z));
      o.w = f2bf(log1p_fast(v.w));
      reinterpret_cast<ushort4*>(h)[i] = o;
    }
  } else {
    int idx = (bid - STRIPE1_TOT) * 256 + threadIdx.x;
    const int SZ0 = DIM_IN * 256;
    const int SZ1 = DIM_H * 256;
    if (idx < SZ0) pack_one(W0s, o0s, idx, false);
    else if (idx < 2 * SZ0) pack_one(W0n, o0n, idx - SZ0, false);
    else if (idx < PACK_TOT) {
      int j = idx - 2 * SZ0;
      int w = j / SZ1, local = j - w * SZ1;
      if (w == 0) pack_one(W1s, o1s, local, true);
      else if (w == 1) pack_one(W1n, o1n, local, true);
      else if (w == 2) pack_one(W2s, o2s, local, true);
      else pack_one(W2n, o2n, local, true);
    }
  }
}

// ---------------- hierarchical scan ----------------
__global__ void scan1_kernel(const int* __restrict__ deg, int* __restrict__ tmp,
                             int* __restrict__ bsum) {
  __shared__ int buf[256];
  int t = threadIdx.x, i = blockIdx.x * 256 + t;
  int v = (i < N_NODES) ? deg[i] : 0;
  buf[t] = v;
  __syncthreads();
  int x = v;
#pragma unroll
  for (int off = 1; off < 256; off <<= 1) {
    int y = (t >= off) ? buf[t - off] : 0;
    __syncthreads();
    x += y;
    buf[t] = x;
    __syncthreads();
  }
  if (i < N_NODES) tmp[i] = x - v;
  if (t == 255) bsum[blockIdx.x] = x;
}

__global__ void scan2_kernel(int* __restrict__ bsum, int nb) {
  __shared__ int buf[256];
  int t = threadIdx.x;
  int v = (t < nb) ? bsum[t] : 0;
  buf[t] = v;
  __syncthreads();
  int x = v;
#pragma unroll
  for (int off = 1; off < 256; off <<= 1) {
    int y = (t >= off) ? buf[t - off] : 0;
    __syncthreads();
    x += y;
    buf[t] = x;
    __syncthreads();
  }
  if (t < nb) bsum[t] = x - v;
}

__global__ void scan3_kernel(const int* __restrict__ tmp, const int* __restrict__ bsum,
                             int* __restrict__ rowptr, int* __restrict__ cursor) {
  int i = blockIdx.x * 256 + threadIdx.x;
  if (i >= N_NODES) return;
  int r = tmp[i] + bsum[i >> 8];
  rowptr[i] = r;
  cursor[i] = r;
}

// ---------------- dual GEMM body: S = bf16(A@Ws + b), Yq = int8(A@Wn) ----------------
template <int K>
static __device__ void gemm_dual_body(int blk, ushort* Al, ushort* Bl, float* red,
                                      const ushort* __restrict__ A,
                                      const ushort* __restrict__ Bs,
                                      const ushort* __restrict__ Bn,
                                      const float* __restrict__ bias,
                                      ushort* __restrict__ Sout,
                                      unsigned char* __restrict__ Yq,
                                      float* __restrict__ scales) {
  constexpr int KC = K / 32;
  constexpr int NT = 2 * KC;
  const int tid = threadIdx.x;
  const int wv = tid >> 6, lane = tid & 63, lj = lane & 15, lg = lane >> 4;
  const int wm = wv >> 1, wn = wv & 1;
  const int r0 = blk * 128;

  int grow[2], akgd[2];
#pragma unroll
  for (int j = 0; j < 2; ++j) {
    int d = tid + j * 256;
    int row = d >> 2, kgs = d & 3;
    akgd[j] = kgs ^ ((row >> 1) & 3);
    int r = r0 + row;
    grow[j] = r < N_NODES ? r : N_NODES - 1;
  }

  int aoff[4], boff[8];
#pragma unroll
  for (int mf = 0; mf < 4; ++mf) {
    int row = wm * 64 + mf * 16 + lj;
    aoff[mf] = row * 32 + (lg ^ ((row >> 1) & 3)) * 8;
  }
#pragma unroll
  for (int f = 0; f < 8; ++f) {
    int col = wn * 128 + f * 16 + lj;
    boff[f] = col * 32 + (lg ^ ((col >> 1) & 3)) * 8;
  }

  auto stage = [&](int t, int bb) {
    int p = t >= KC;
    int kc = t - p * KC;
    const ushort* Bp = p ? Bn : Bs;
#pragma unroll
    for (int j = 0; j < 2; ++j)
      gload16(A + (size_t)grow[j] * K + kc * 32 + akgd[j] * 8,
              (char*)(Al + bb * 4096) + j * 4096 + wv * 1024);
#pragma unroll
    for (int j = 0; j < 4; ++j)
      gload16(Bp + (size_t)kc * 8192 + (tid + j * 256) * 8,
              (char*)(Bl + bb * 8192) + j * 4096 + wv * 1024);
  };

  float bvv[8];
#pragma unroll
  for (int f = 0; f < 8; ++f) bvv[f] = bias[wn * 128 + f * 16 + lj];

  f32x4 acc[4][8];
#pragma unroll
  for (int mf = 0; mf < 4; ++mf)
#pragma unroll
    for (int f = 0; f < 8; ++f) acc[mf][f] = (f32x4){0.f, 0.f, 0.f, 0.f};

  stage(0, 0);
  __syncthreads();
  int b = 0;
  for (int t = 0; t < NT; ++t) {
    if (t + 1 < NT) stage(t + 1, b ^ 1);
    bf16x8 av[4], bv[8];
#pragma unroll
    for (int mf = 0; mf < 4; ++mf)
      av[mf] = *reinterpret_cast<const bf16x8*>(Al + b * 4096 + aoff[mf]);
#pragma unroll
    for (int f = 0; f < 8; ++f)
      bv[f] = *reinterpret_cast<const bf16x8*>(Bl + b * 8192 + boff[f]);
#pragma unroll
    for (int mf = 0; mf < 4; ++mf)
#pragma unroll
      for (int f = 0; f < 8; ++f)
        acc[mf][f] = __builtin_amdgcn_mfma_f32_16x16x32_bf16(av[mf], bv[f], acc[mf][f], 0, 0, 0);
    if (t == KC - 1) {
#pragma unroll
      for (int mf = 0; mf < 4; ++mf)
#pragma unroll
        for (int e = 0; e < 4; ++e) {
          int row = r0 + wm * 64 + mf * 16 + lg * 4 + e;
          if (row < N_NODES) {
            ushort* pS = Sout + (size_t)row * 256 + wn * 128 + lj * 8;
            uint4 o;
            o.x = (uint)f2bf(acc[mf][0][e] + bvv[0]) | ((uint)f2bf(acc[mf][1][e] + bvv[1]) << 16);
            o.y = (uint)f2bf(acc[mf][2][e] + bvv[2]) | ((uint)f2bf(acc[mf][3][e] + bvv[3]) << 16);
            o.z = (uint)f2bf(acc[mf][4][e] + bvv[4]) | ((uint)f2bf(acc[mf][5][e] + bvv[5]) << 16);
            o.w = (uint)f2bf(acc[mf][6][e] + bvv[6]) | ((uint)f2bf(acc[mf][7][e] + bvv[7]) << 16);
            *reinterpret_cast<uint4*>(pS) = o;
          }
        }
#pragma unroll
      for (int mf = 0; mf < 4; ++mf)
#pragma unroll
        for (int f = 0; f < 8; ++f) acc[mf][f] = (f32x4){0.f, 0.f, 0.f, 0.f};
    }
    __syncthreads();
    b ^= 1;
  }

  float rmax[4][4];
#pragma unroll
  for (int mf = 0; mf < 4; ++mf)
#pragma unroll
    for (int e = 0; e < 4; ++e) {
      float m = 0.f;
#pragma unroll
      for (int f = 0; f < 8; ++f) m = fmaxf(m, fabsf(acc[mf][f][e]));
      m = fmaxf(m, __shfl_xor(m, 1));
      m = fmaxf(m, __shfl_xor(m, 2));
      m = fmaxf(m, __shfl_xor(m, 4));
      m = fmaxf(m, __shfl_xor(m, 8));
      rmax[mf][e] = m;
    }
  if (lj == 0) {
#pragma unroll
    for (int mf = 0; mf < 4; ++mf)
#pragma unroll
      for (int e = 0; e < 4; ++e)
        red[(wn * 2 + wm) * 64 + mf * 16 + lg * 4 + e] = rmax[mf][e];
  }
  __syncthreads();
#pragma unroll
  for (int mf = 0; mf < 4; ++mf)
#pragma unroll
    for (int e = 0; e < 4; ++e) {
      float m = fmaxf(fmaxf(red[(0 * 2 + wm) * 64 + mf * 16 + lg * 4 + e],
                            red[(1 * 2 + wm) * 64 + mf * 16 + lg * 4 + e]), 1e-30f);
      float inv_s = 127.0f / m;
      int row = r0 + wm * 64 + mf * 16 + lg * 4 + e;
      if (row < N_NODES) {
        uint lo = 0, hi = 0;
#pragma unroll
        for (int f = 0; f < 4; ++f) {
          int q = (int)rintf(acc[mf][f][e] * inv_s) + 128;
          q = max(0, min(255, q));
          lo |= (uint)q << (8 * f);
        }
#pragma unroll
        for (int f = 4; f < 8; ++f) {
          int q = (int)rintf(acc[mf][f][e] * inv_s) + 128;
          q = max(0, min(255, q));
          hi |= (uint)q << (8 * (f - 4));
        }
        *reinterpret_cast<uint2*>(Yq + (size_t)row * 256 + wn * 128 + lj * 8) = make_uint2(lo, hi);
        if (wn == 0 && lj == 0) scales[row] = m * (1.0f / 127.0f);
      }
    }
}

// ---------------- striped {gemm0 : CSR fill}, 1:2 ratio, 4 edges/thread ----------------
// __launch_bounds__(256,2): acc[4][8] needs ~128 AGPR + ~120 VGPR; (256,3) spills (R10).
#define GEMM_BLOCKS ((N_NODES + 127) / 128)     // 391
#define GF_TOT (GEMM_BLOCKS * 3)                // {1 gemm, 2 fill}; 782 fill x 1024 edges

__global__ __launch_bounds__(256, 2) void gemm0_fill_kernel(
    const ushort* __restrict__ A, const ushort* __restrict__ Bs,
    const ushort* __restrict__ Bn, const float* __restrict__ bias,
    ushort* __restrict__ Sout, unsigned char* __restrict__ Yq, float* __restrict__ scales,
    const int* __restrict__ src, const int* __restrict__ dst,
    int* __restrict__ cursor, ushort* __restrict__ csr) {
  __shared__ ushort Al[2 * 4096];
  __shared__ ushort Bl[2 * 8192];
  __shared__ float red[256];
  int g = blockIdx.x / 3, r = blockIdx.x - g * 3;
  if (r == 0) {
    gemm_dual_body<DIM_IN>(g, Al, Bl, red, A, Bs, Bn, bias, Sout, Yq, scales);
  } else {
    int fb = g * 2 + (r - 1);
    int base = fb * 1024 + threadIdx.x * 4;
    if (base + 3 < N_EDGES) {
      int4 d4 = *reinterpret_cast<const int4*>(dst + base);
      int4 s4 = *reinterpret_cast<const int4*>(src + base);
      int p0 = atomicAdd(&cursor[d4.x], 1);
      int p1 = atomicAdd(&cursor[d4.y], 1);
      int p2 = atomicAdd(&cursor[d4.z], 1);
      int p3 = atomicAdd(&cursor[d4.w], 1);
      csr[p0] = (ushort)s4.x;
      csr[p1] = (ushort)s4.y;
      csr[p2] = (ushort)s4.z;
      csr[p3] = (ushort)s4.w;
    } else {
#pragma unroll
      for (int j = 0; j < 4; ++j) {
        int i = base + j;
        if (i < N_EDGES) {
          int d = dst[i];
          int p = atomicAdd(&cursor[d], 1);
          csr[p] = (ushort)src[i];
        }
      }
    }
  }
}

__global__ __launch_bounds__(256, 2) void gemm_dual_kernel(
    const ushort* __restrict__ A, const ushort* __restrict__ Bs,
    const ushort* __restrict__ Bn, const float* __restrict__ bias,
    ushort* __restrict__ Sout, unsigned char* __restrict__ Yq, float* __restrict__ scales) {
  __shared__ ushort Al[2 * 4096];
  __shared__ ushort Bl[2 * 8192];
  __shared__ float red[256];
  gemm_dual_body<DIM_H>(blockIdx.x, Al, Bl, red, A, Bs, Bn, bias, Sout, Yq, scales);
}

// ---------------- gather: out = epilogue(S + mean(dequant(Yq[src]))) ----------------
template <bool FINAL>
__global__ __launch_bounds__(256) void gather_kernel(const unsigned char* __restrict__ Yq,
                                                     const float* __restrict__ scales,
                                                     const ushort* __restrict__ Sin,
                                                     const int* __restrict__ rowptr,
                                                     const int* __restrict__ deg,
                                                     const ushort* __restrict__ csr,
                                                     void* __restrict__ outv) {
  int node = blockIdx.x * 8 + (threadIdx.x >> 5);
  if (node >= N_NODES) return;
  int hl = threadIdx.x & 31;
  int start = rowptr[node];
  int d = deg[node];
  float acc[8];
#pragma unroll
  for (int i = 0; i < 8; ++i) acc[i] = 0.0f;
  float stot = 0.f;

  auto ub = [](uint u, int j) { return (float)((u >> (8 * j)) & 0xffu); };
  int e = 0;
  for (; e + 4 <= d; e += 4) {
    int s0 = csr[start + e], s1 = csr[start + e + 1];
    int s2 = csr[start + e + 2], s3 = csr[start + e + 3];
    float c0 = scales[s0], c1 = scales[s1], c2 = scales[s2], c3 = scales[s3];
    uint2 q0 = *reinterpret_cast<const uint2*>(Yq + (size_t)s0 * 256 + hl * 8);
    uint2 q1 = *reinterpret_cast<const uint2*>(Yq + (size_t)s1 * 256 + hl * 8);
    uint2 q2 = *reinterpret_cast<const uint2*>(Yq + (size_t)s2 * 256 + hl * 8);
    uint2 q3 = *reinterpret_cast<const uint2*>(Yq + (size_t)s3 * 256 + hl * 8);
    stot += c0 + c1 + c2 + c3;
#pragma unroll
    for (int j = 0; j < 4; ++j) {
      acc[j]     += c0 * ub(q0.x, j) + c1 * ub(q1.x, j) + c2 * ub(q2.x, j) + c3 * ub(q3.x, j);
      acc[4 + j] += c0 * ub(q0.y, j) + c1 * ub(q1.y, j) + c2 * ub(q2.y, j) + c3 * ub(q3.y, j);
    }
  }
  for (; e < d; ++e) {
    int s = csr[start + e];
    float c = scales[s];
    uint2 q = *reinterpret_cast<const uint2*>(Yq + (size_t)s * 256 + hl * 8);
    stot += c;
#pragma unroll
    for (int j = 0; j < 4; ++j) {
      acc[j]     += c * ub(q.x, j);
      acc[4 + j] += c * ub(q.y, j);
    }
  }

  float invd = 1.0f / fmaxf((float)d, 1.0f);
  float nb[8];
#pragma unroll
  for (int j = 0; j < 8; ++j) nb[j] = (acc[j] - 128.0f * stot) * invd;

  uint4 sv = *reinterpret_cast<const uint4*>(Sin + (size_t)node * 256 + hl * 8);
  uint su[4] = {sv.x, sv.y, sv.z, sv.w};

  if constexpr (FINAL) {
    float* out = (float*)outv + (size_t)node * 256 + (hl >> 4) * 128 + (hl & 15);
#pragma unroll
    for (int i = 0; i < 4; ++i) {
      out[(2 * i) * 16]     = nb[2 * i] + bf_lo(su[i]);
      out[(2 * i + 1) * 16] = nb[2 * i + 1] + bf_hi(su[i]);
    }
  } else {
    float v[8];
    float ssq = 0.f;
#pragma unroll
    for (int i = 0; i < 4; ++i) {
      float a = fmaxf(nb[2 * i] + bf_lo(su[i]), 0.0f);
      float b = fmaxf(nb[2 * i + 1] + bf_hi(su[i]), 0.0f);
      v[2 * i] = a; v[2 * i + 1] = b;
      ssq += a * a + b * b;
    }
    ssq += __shfl_xor(ssq, 1);
    ssq += __shfl_xor(ssq, 2);
    ssq += __shfl_xor(ssq, 4);
    ssq += __shfl_xor(ssq, 8);
    ssq += __shfl_xor(ssq, 16);
    float rn = 1.0f / fmaxf(sqrtf(ssq), 1e-12f);
    uint o[4];
#pragma unroll
    for (int i = 0; i < 4; ++i) {
      uint lo = f2bf(v[2 * i] * rn);
      uint hi = f2bf(v[2 * i + 1] * rn);
      o[i] = lo | (hi << 16);
    }
    *reinterpret_cast<uint4*>((ushort*)outv + (size_t)node * 256 + hl * 8) =
        make_uint4(o[0], o[1], o[2], o[3]);
  }
}

// ---------------- launch ----------------
extern "C" void kernel_launch(void* const* d_in, const int* in_sizes, int n_in,
                              void* d_out, int out_size, void* d_ws, size_t ws_size,
                              hipStream_t stream) {
  const float* x   = (const float*)d_in[0];
  const int*   src = (const int*)d_in[1];
  const int*   dst = (const int*)d_in[2];
  const float* Ws0 = (const float*)d_in[3];
  const float* Wn0 = (const float*)d_in[4];
  const float* b0  = (const float*)d_in[5];
  const float* Ws1 = (const float*)d_in[6];
  const float* Wn1 = (const float*)d_in[7];
  const float* b1  = (const float*)d_in[8];
  const float* Ws2 = (const float*)d_in[9];
  const float* Wn2 = (const float*)d_in[10];
  const float* b2  = (const float*)d_in[11];

  uintptr_t p = ((uintptr_t)d_ws + 255) & ~(uintptr_t)255;
  auto carve = [&](size_t bytes) {
    void* r = (void*)p;
    p += (bytes + 255) & ~(size_t)255;
    return r;
  };
  ushort* h0 = (ushort*)carve((size_t)N_NODES * DIM_IN * 2);
  ushort* h2 = h0;
  ushort* S_mid = (ushort*)carve((size_t)N_NODES * DIM_H * 2);
  ushort* h1 = (ushort*)carve((size_t)N_NODES * DIM_H * 2);
  unsigned char* Yq = (unsigned char*)carve((size_t)N_NODES * 256);
  float* scales = (float*)carve((size_t)N_NODES * 4);
  ushort* Ws0p = (ushort*)carve((size_t)DIM_IN * 256 * 2);
  ushort* Wn0p = (ushort*)carve((size_t)DIM_IN * 256 * 2);
  ushort* Ws1p = (ushort*)carve((size_t)DIM_H * 256 * 2);
  ushort* Wn1p = (ushort*)carve((size_t)DIM_H * 256 * 2);
  ushort* Ws2p = (ushort*)carve((size_t)DIM_H * 256 * 2);
  ushort* Wn2p = (ushort*)carve((size_t)DIM_H * 256 * 2);
  int* deg    = (int*)carve((size_t)N_NODES * 4);
  int* rowptr = (int*)carve((size_t)N_NODES * 4);
  int* cursor = (int*)carve((size_t)N_NODES * 4);
  int* stmp   = (int*)carve((size_t)N_NODES * 4);
  int* bsum   = (int*)carve(256 * 4);
  ushort* csr = (ushort*)carve((size_t)N_EDGES * 2);

  hipMemsetAsync(deg, 0, (size_t)N_NODES * 4, stream);

  prep_kernel<<<STRIPE1_TOT + PACK_BLOCKS, 256, 0, stream>>>(
      x, h0, dst, deg, Ws0, Wn0, Ws1, Wn1, Ws2, Wn2,
      Ws0p, Wn0p, Ws1p, Wn1p, Ws2p, Wn2p);

  const int scanBlocks = (N_NODES + 255) / 256;
  scan1_kernel<<<scanBlocks, 256, 0, stream>>>(deg, stmp, bsum);
  scan2_kernel<<<1, 256, 0, stream>>>(bsum, scanBlocks);
  scan3_kernel<<<scanBlocks, 256, 0, stream>>>(stmp, bsum, rowptr, cursor);

  gemm0_fill_kernel<<<GF_TOT, 256, 0, stream>>>(
      h0, Ws0p, Wn0p, b0, S_mid, Yq, scales, src, dst, cursor, csr);

  const int gatherBlocks = (N_NODES + 7) / 8;

  gather_kernel<false><<<gatherBlocks, 256, 0, stream>>>(Yq, scales, S_mid, rowptr, deg, csr, h1);
  gemm_dual_kernel<<<GEMM_BLOCKS, 256, 0, stream>>>(h1, Ws1p, Wn1p, b1, S_mid, Yq, scales);
  gather_kernel<false><<<gatherBlocks, 256, 0, stream>>>(Yq, scales, S_mid, rowptr, deg, csr, h2);
  gemm_dual_kernel<<<GEMM_BLOCKS, 256, 0, stream>>>(h2, Ws2p, Wn2p, b2, S_mid, Yq, scales);
  gather_kernel<true><<<gatherBlocks, 256, 0, stream>>>(Yq, scales, S_mid, rowptr, deg, csr, d_out);
}